// Round 2
// baseline (12822.318 us; speedup 1.0000x reference)
//
#include <hip/hip_runtime.h>

typedef unsigned short ushort;
typedef __attribute__((ext_vector_type(8))) short short8;
typedef __attribute__((ext_vector_type(4))) float f32x4;
typedef __attribute__((ext_vector_type(4))) unsigned short us4;

// Problem constants
#define BB 32
#define TT 512
#define DIN 512
#define HH 1024
#define CHUNK 128   // time steps per chunk (4 chunks)

__device__ __forceinline__ ushort f2b(float f) {
  unsigned u = __builtin_bit_cast(unsigned, f);
  unsigned r = (u + 0x7fffu + ((u >> 16) & 1u)) >> 16;
  return (ushort)r;
}

// ---------------------------------------------------------------- init
// zero h1 slot0 (16384 u32), h2 slot0 (16384 u32), flags (2x64)
__global__ __launch_bounds__(256) void init_k(unsigned int* h1s, unsigned int* h2s,
                                              int* f0, int* f1) {
  int i = blockIdx.x * 256 + threadIdx.x;   // grid 128 -> 32768 threads
  if (i < 16384) h1s[i] = 0u;
  else h2s[i - 16384] = 0u;
  if (i < 64) f0[i] = 0;
  else if (i < 128) f1[i - 64] = 0;
}

// ---------------------------------------------------------------- fp32 -> bf16 cast
__global__ __launch_bounds__(256) void cast_k(const float* __restrict__ in,
                                              ushort* __restrict__ out, int n4) {
  int i = blockIdx.x * 256 + threadIdx.x;
  if (i < n4) {
    float4 v = ((const float4*)in)[i];
    us4 o;
    o.x = f2b(v.x); o.y = f2b(v.y); o.z = f2b(v.z); o.w = f2b(v.w);
    ((us4*)out)[i] = o;
  }
}

// ---------------------------------------------------------------- bf16 GEMM  C = A @ B^T
// M = 4096 (one time chunk: 128 steps x 32 batch, t-major rows), N = 3072, K param.
// AF32=1: A is fp32 x [B,T,DIN], row m -> x[(m&31)*TT + tOff + (m>>5)], cast on the fly.
// AF32=0: A is bf16 row-major [4096][K].
// Tile 128x128, BK=64, 256 thr = 4 waves, each wave 64x64.
template <int AF32>
__global__ __launch_bounds__(256) void gemm_bt(const void* __restrict__ Ap,
                                               const ushort* __restrict__ B,
                                               float* __restrict__ C,
                                               int N, int K, int tOff) {
  __shared__ __align__(16) ushort As[128 * 72];
  __shared__ __align__(16) ushort Bs[128 * 72];
  const int tid = threadIdx.x;
  const int lane = tid & 63, wave = tid >> 6;
  const int wm = wave >> 1, wn = wave & 1;
  const int bm = blockIdx.y << 7, bn = blockIdx.x << 7;

  const int srow = tid >> 3;        // 0..31 staging row
  const int sdst = (tid & 7) << 3;  // elem offset within row (8-elem chunks)
  size_t aoff[4], boff[4];
#pragma unroll
  for (int i = 0; i < 4; ++i) {
    int m = bm + srow + (i << 5);
    if (AF32) aoff[i] = ((size_t)(m & 31) * TT + tOff + (m >> 5)) * (size_t)K;
    else      aoff[i] = (size_t)m * K;
    boff[i] = (size_t)(bn + srow + (i << 5)) * K;
  }

  const int fr = lane & 15, fq = lane >> 4;
  int aofl[4], bofl[4];
#pragma unroll
  for (int m = 0; m < 4; ++m) {
    aofl[m] = ((wm << 6) + (m << 4) + fr) * 72 + (fq << 3);
    bofl[m] = ((wn << 6) + (m << 4) + fr) * 72 + (fq << 3);
  }

  f32x4 acc[4][4] = {};
  for (int k0 = 0; k0 < K; k0 += 64) {
#pragma unroll
    for (int i = 0; i < 4; ++i) {
      int row = srow + (i << 5);
      if (AF32) {
        const float* A32 = (const float*)Ap;
        float4 v0 = *(const float4*)&A32[aoff[i] + k0 + sdst];
        float4 v1 = *(const float4*)&A32[aoff[i] + k0 + sdst + 4];
        us4 lo, hi;
        lo.x = f2b(v0.x); lo.y = f2b(v0.y); lo.z = f2b(v0.z); lo.w = f2b(v0.w);
        hi.x = f2b(v1.x); hi.y = f2b(v1.y); hi.z = f2b(v1.z); hi.w = f2b(v1.w);
        *(us4*)&As[row * 72 + sdst] = lo;
        *(us4*)&As[row * 72 + sdst + 4] = hi;
      } else {
        *(short8*)&As[row * 72 + sdst] = *(const short8*)&((const ushort*)Ap)[aoff[i] + k0 + sdst];
      }
      *(short8*)&Bs[row * 72 + sdst] = *(const short8*)&B[boff[i] + k0 + sdst];
    }
    __syncthreads();
#pragma unroll
    for (int kk = 0; kk < 2; ++kk) {
      short8 af[4], bf[4];
#pragma unroll
      for (int m = 0; m < 4; ++m) af[m] = *(const short8*)&As[aofl[m] + kk * 32];
#pragma unroll
      for (int n = 0; n < 4; ++n) bf[n] = *(const short8*)&Bs[bofl[n] + kk * 32];
#pragma unroll
      for (int m = 0; m < 4; ++m)
#pragma unroll
        for (int n = 0; n < 4; ++n)
          acc[m][n] = __builtin_amdgcn_mfma_f32_16x16x32_bf16(af[m], bf[n], acc[m][n], 0, 0, 0);
    }
    __syncthreads();
  }
#pragma unroll
  for (int m = 0; m < 4; ++m) {
    int row0 = bm + (wm << 6) + (m << 4) + (fq << 2);
#pragma unroll
    for (int n = 0; n < 4; ++n) {
      int col = bn + (wn << 6) + (n << 4) + fr;
#pragma unroll
      for (int r = 0; r < 4; ++r)
        C[(size_t)(row0 + r) * N + col] = acc[m][n][r];
    }
  }
}

// ---------------------------------------------------------------- persistent GRU layer (chunked)
// 64 WGs x 64 threads (1 wave). WG owns h-columns [16*wg, 16*wg+16).
// W_hh slice (48 rows x 1024) in LDS; fp32 own-state in registers (hstate across chunks).
// Steps t in [t0, tEnd). h exchange via bf16 hseq slots (slot index = t & slotMask).
__global__ __launch_bounds__(64) void gru_layer(const ushort* __restrict__ W,
                                                const float* __restrict__ bih,
                                                const float* __restrict__ bhh,
                                                const float* __restrict__ xp,
                                                ushort* __restrict__ hseq,
                                                float* __restrict__ hstate,
                                                int* __restrict__ flags,
                                                int t0, int tEnd, int slotMask) {
  __shared__ __align__(16) ushort Wl[48 * 1032];   // rows padded +8
  const int lane = threadIdx.x;
  const int c0 = blockIdx.x << 4;

  for (int q = lane; q < 6144; q += 64) {          // 16B chunks: 48 rows x 128 chunks
    int i = q >> 7, k8 = (q & 127) << 3;
    int g = i >> 4, cc = i & 15;
    *(short8*)&Wl[i * 1032 + k8] = *(const short8*)&W[(size_t)(g * 1024 + c0 + cc) * 1024 + k8];
  }

  const int c = c0 + (lane & 15);
  const float bhr = bhh[c], bhz = bhh[1024 + c], bhn = bhh[2048 + c];
  const float bir = bih[c], biz = bih[1024 + c], bin_ = bih[2048 + c];
  const int ko = (lane >> 4) << 3;
  const int wb0 = (lane & 15) * 1032 + ko;
  const int wb1 = (16 + (lane & 15)) * 1032 + ko;
  const int wb2 = (32 + (lane & 15)) * 1032 + ko;

  float hl[2][4];
#pragma unroll
  for (int mt = 0; mt < 2; ++mt)
#pragma unroll
    for (int r = 0; r < 4; ++r) {
      int b = (mt << 4) + ((lane >> 4) << 2) + r;
      hl[mt][r] = (t0 == 0) ? 0.f : hstate[b * HH + c];
    }
  __syncthreads();

  for (int t = t0; t < tEnd; ++t) {
    const int lt = t - t0;
    // prefetch gate inputs (stable memory, safe before barrier)
    const float* xpt = xp + (size_t)lt * (BB * 3 * HH);
    float xr[2][4], xz[2][4], xn[2][4];
#pragma unroll
    for (int mt = 0; mt < 2; ++mt)
#pragma unroll
      for (int r = 0; r < 4; ++r) {
        int b = (mt << 4) + ((lane >> 4) << 2) + r;
        const float* p = xpt + (size_t)b * (3 * HH) + c;
        xr[mt][r] = p[0]; xz[mt][r] = p[HH]; xn[mt][r] = p[2 * HH];
      }

    if (t > t0) {  // wait for all WGs to have published h[t]
      int v;
      do {
        v = __hip_atomic_load(flags + lane, __ATOMIC_RELAXED, __HIP_MEMORY_SCOPE_AGENT);
        if (v < t) __builtin_amdgcn_s_sleep(1);
      } while (__any(v < t));
      __threadfence();   // agent acquire: invalidate so h loads see fresh data
    }

    f32x4 acc[2][3] = {};
    const ushort* h0p = hseq + (size_t)(t & slotMask) * (BB * HH) + (size_t)(lane & 15) * HH + ko;
    const ushort* h1p = h0p + 16 * HH;
#pragma unroll 4
    for (int kk = 0; kk < 32; ++kk) {
      short8 a0 = *(const short8*)(h0p + kk * 32);
      short8 a1 = *(const short8*)(h1p + kk * 32);
      short8 br = *(const short8*)&Wl[wb0 + kk * 32];
      short8 bz = *(const short8*)&Wl[wb1 + kk * 32];
      short8 bn = *(const short8*)&Wl[wb2 + kk * 32];
      acc[0][0] = __builtin_amdgcn_mfma_f32_16x16x32_bf16(a0, br, acc[0][0], 0, 0, 0);
      acc[1][0] = __builtin_amdgcn_mfma_f32_16x16x32_bf16(a1, br, acc[1][0], 0, 0, 0);
      acc[0][1] = __builtin_amdgcn_mfma_f32_16x16x32_bf16(a0, bz, acc[0][1], 0, 0, 0);
      acc[1][1] = __builtin_amdgcn_mfma_f32_16x16x32_bf16(a1, bz, acc[1][1], 0, 0, 0);
      acc[0][2] = __builtin_amdgcn_mfma_f32_16x16x32_bf16(a0, bn, acc[0][2], 0, 0, 0);
      acc[1][2] = __builtin_amdgcn_mfma_f32_16x16x32_bf16(a1, bn, acc[1][2], 0, 0, 0);
    }

    ushort* hw = hseq + (size_t)((t + 1) & slotMask) * (BB * HH);
#pragma unroll
    for (int mt = 0; mt < 2; ++mt)
#pragma unroll
      for (int r = 0; r < 4; ++r) {
        int b = (mt << 4) + ((lane >> 4) << 2) + r;
        float hr = acc[mt][0][r] + bhr;
        float hz = acc[mt][1][r] + bhz;
        float hn = acc[mt][2][r] + bhn;
        float rv = 1.f / (1.f + __expf(-(xr[mt][r] + bir + hr)));
        float zv = 1.f / (1.f + __expf(-(xz[mt][r] + biz + hz)));
        float nv = tanhf(xn[mt][r] + bin_ + rv * hn);
        float h = (1.f - zv) * nv + zv * hl[mt][r];
        hl[mt][r] = h;
        hw[(size_t)b * HH + c] = f2b(h);
      }

    if (t == tEnd - 1) {
      // kernel boundary provides coherence for the next launch
#pragma unroll
      for (int mt = 0; mt < 2; ++mt)
#pragma unroll
        for (int r = 0; r < 4; ++r) {
          int b = (mt << 4) + ((lane >> 4) << 2) + r;
          hstate[b * HH + c] = hl[mt][r];
        }
    } else {
      __threadfence();   // agent release: make h stores visible before flag
      if (lane == 0)
        __hip_atomic_store(flags + blockIdx.x, t + 1, __ATOMIC_RELAXED, __HIP_MEMORY_SCOPE_AGENT);
    }
  }
}

// ---------------------------------------------------------------- final FC
__global__ __launch_bounds__(256) void fc_k(const float* __restrict__ h,
                                            const float* __restrict__ Wf,
                                            const float* __restrict__ bf,
                                            float* __restrict__ out) {
  int idx = blockIdx.x * 256 + threadIdx.x;   // grid 64 -> 16384 = 32x512
  int b = idx >> 9, o = idx & 511;
  const float4* hv = (const float4*)(h + (b << 10));
  const float4* wv = (const float4*)(Wf + (o << 10));
  float s = 0.f;
#pragma unroll 8
  for (int i = 0; i < 256; ++i) {
    float4 x = hv[i], y = wv[i];
    s += x.x * y.x + x.y * y.y + x.z * y.z + x.w * y.w;
  }
  out[idx] = s + bf[o];
}

// ---------------------------------------------------------------- launch
extern "C" void kernel_launch(void* const* d_in, const int* in_sizes, int n_in,
                              void* d_out, int out_size, void* d_ws, size_t ws_size,
                              hipStream_t stream) {
  const float* x    = (const float*)d_in[0];
  const float* Wih0 = (const float*)d_in[1];
  const float* Whh0 = (const float*)d_in[2];
  const float* bih0 = (const float*)d_in[3];
  const float* bhh0 = (const float*)d_in[4];
  const float* Wih1 = (const float*)d_in[5];
  const float* Whh1 = (const float*)d_in[6];
  const float* bih1 = (const float*)d_in[7];
  const float* bhh1 = (const float*)d_in[8];
  const float* Wfc  = (const float*)d_in[9];
  const float* bfc  = (const float*)d_in[10];
  float* out = (float*)d_out;

  // workspace layout (total ~101.4 MiB)
  char* w = (char*)d_ws;
  ushort* wi0b = (ushort*)(w);                    //  3,145,728
  ushort* wh0b = (ushort*)(w + 3145728);          //  6,291,456
  ushort* wi1b = (ushort*)(w + 9437184);          //  6,291,456
  ushort* wh1b = (ushort*)(w + 15728640);         //  6,291,456
  float*  xp   = (float*)(w + 22020096);          // 50,331,648  one chunk [128,B,3H] fp32
  ushort* h1   = (ushort*)(w + 72351744);         // 33,619,968  full seq [(T+1),B,H] bf16
  ushort* h2   = (ushort*)(w + 105971712);        //    131,072  2 slots
  float*  hs0  = (float*)(w + 106102784);         //    131,072  fp32 h state L0
  float*  hs1  = (float*)(w + 106233856);         //    131,072  fp32 h state L1
  int*    flg0 = (int*)(w + 106364928);           //        256
  int*    flg1 = (int*)(w + 106365184);           //        256

  init_k<<<128, 256, 0, stream>>>((unsigned int*)h1, (unsigned int*)h2, flg0, flg1);

  cast_k<<<1536, 256, 0, stream>>>(Wih0, wi0b, (3 * HH * DIN) / 4);
  cast_k<<<3072, 256, 0, stream>>>(Whh0, wh0b, (3 * HH * HH) / 4);
  cast_k<<<3072, 256, 0, stream>>>(Wih1, wi1b, (3 * HH * HH) / 4);
  cast_k<<<3072, 256, 0, stream>>>(Whh1, wh1b, (3 * HH * HH) / 4);

  for (int ch = 0; ch < 4; ++ch) {
    const int t0 = ch * CHUNK, t1 = (ch + 1) * CHUNK;
    // x_proj0 chunk: [128*32, 3H] fp32 <- x(fp32, cast on the fly) @ Wih0^T
    gemm_bt<1><<<dim3(24, 32), 256, 0, stream>>>(x, wi0b, xp, 3 * HH, DIN, t0);
    // layer 0 recurrence over chunk -> h1 slots t0+1 .. t1
    gru_layer<<<64, 64, 0, stream>>>(wh0b, bih0, bhh0, xp, h1, hs0, flg0, t0, t1, 0x7fffffff);
    // x_proj1 chunk <- h1 slots [t0+1 .. t1] @ Wih1^T
    gemm_bt<0><<<dim3(24, 32), 256, 0, stream>>>(h1 + (size_t)(t0 + 1) * BB * HH, wi1b, xp,
                                                 3 * HH, HH, 0);
    // layer 1 recurrence over chunk (2-slot h exchange)
    gru_layer<<<64, 64, 0, stream>>>(wh1b, bih1, bhh1, xp, h2, hs1, flg1, t0, t1, 1);
  }

  fc_k<<<64, 256, 0, stream>>>(hs1, Wfc, bfc, out);
}

// Round 3
// 7512.232 us; speedup vs baseline: 1.7069x; 1.7069x over previous
//
#include <hip/hip_runtime.h>

typedef unsigned short ushort;
typedef __attribute__((ext_vector_type(8))) short short8;
typedef __attribute__((ext_vector_type(4))) float f32x4;
typedef __attribute__((ext_vector_type(4))) unsigned short us4;

// Problem constants
#define BB 32
#define TT 512
#define DIN 512
#define HH 1024
#define CHUNK 128   // time steps per chunk (4 chunks)

__device__ __forceinline__ ushort f2b(float f) {
  unsigned u = __builtin_bit_cast(unsigned, f);
  unsigned r = (u + 0x7fffu + ((u >> 16) & 1u)) >> 16;
  return (ushort)r;
}

#define MFMA16(a, b, c) __builtin_amdgcn_mfma_f32_16x16x32_bf16(a, b, c, 0, 0, 0)

// ---------------------------------------------------------------- init
__global__ __launch_bounds__(256) void init_k(unsigned int* h1s, unsigned int* h2s,
                                              int* f0, int* f1) {
  int i = blockIdx.x * 256 + threadIdx.x;   // grid 128 -> 32768 threads
  if (i < 16384) h1s[i] = 0u;               // h1 slot 0 (32768 bf16)
  else h2s[i - 16384] = 0u;                 // h2 slot 0
  if (i < 64) f0[i] = 0;
  else if (i < 128) f1[i - 64] = 0;
}

// ---------------------------------------------------------------- fp32 -> bf16 cast
__global__ __launch_bounds__(256) void cast_k(const float* __restrict__ in,
                                              ushort* __restrict__ out, int n4) {
  int i = blockIdx.x * 256 + threadIdx.x;
  if (i < n4) {
    float4 v = ((const float4*)in)[i];
    us4 o;
    o.x = f2b(v.x); o.y = f2b(v.y); o.z = f2b(v.z); o.w = f2b(v.w);
    ((us4*)out)[i] = o;
  }
}

// ---------------------------------------------------------------- bf16 GEMM  C = A @ B^T
// M = 4096 (128 steps x 32 batch, t-major), N = 3072.
// AF32=1: A is fp32 x [B,T,DIN], row m -> x[(m&31)*TT + tOff + (m>>5)], cast on the fly.
template <int AF32>
__global__ __launch_bounds__(256) void gemm_bt(const void* __restrict__ Ap,
                                               const ushort* __restrict__ B,
                                               float* __restrict__ C,
                                               int N, int K, int tOff) {
  __shared__ __align__(16) ushort As[128 * 72];
  __shared__ __align__(16) ushort Bs[128 * 72];
  const int tid = threadIdx.x;
  const int lane = tid & 63, wave = tid >> 6;
  const int wm = wave >> 1, wn = wave & 1;
  const int bm = blockIdx.y << 7, bn = blockIdx.x << 7;

  const int srow = tid >> 3;
  const int sdst = (tid & 7) << 3;
  size_t aoff[4], boff[4];
#pragma unroll
  for (int i = 0; i < 4; ++i) {
    int m = bm + srow + (i << 5);
    if (AF32) aoff[i] = ((size_t)(m & 31) * TT + tOff + (m >> 5)) * (size_t)K;
    else      aoff[i] = (size_t)m * K;
    boff[i] = (size_t)(bn + srow + (i << 5)) * K;
  }

  const int fr = lane & 15, fq = lane >> 4;
  int aofl[4], bofl[4];
#pragma unroll
  for (int m = 0; m < 4; ++m) {
    aofl[m] = ((wm << 6) + (m << 4) + fr) * 72 + (fq << 3);
    bofl[m] = ((wn << 6) + (m << 4) + fr) * 72 + (fq << 3);
  }

  f32x4 acc[4][4] = {};
  for (int k0 = 0; k0 < K; k0 += 64) {
#pragma unroll
    for (int i = 0; i < 4; ++i) {
      int row = srow + (i << 5);
      if (AF32) {
        const float* A32 = (const float*)Ap;
        float4 v0 = *(const float4*)&A32[aoff[i] + k0 + sdst];
        float4 v1 = *(const float4*)&A32[aoff[i] + k0 + sdst + 4];
        us4 lo, hi;
        lo.x = f2b(v0.x); lo.y = f2b(v0.y); lo.z = f2b(v0.z); lo.w = f2b(v0.w);
        hi.x = f2b(v1.x); hi.y = f2b(v1.y); hi.z = f2b(v1.z); hi.w = f2b(v1.w);
        *(us4*)&As[row * 72 + sdst] = lo;
        *(us4*)&As[row * 72 + sdst + 4] = hi;
      } else {
        *(short8*)&As[row * 72 + sdst] = *(const short8*)&((const ushort*)Ap)[aoff[i] + k0 + sdst];
      }
      *(short8*)&Bs[row * 72 + sdst] = *(const short8*)&B[boff[i] + k0 + sdst];
    }
    __syncthreads();
#pragma unroll
    for (int kk = 0; kk < 2; ++kk) {
      short8 af[4], bf[4];
#pragma unroll
      for (int m = 0; m < 4; ++m) af[m] = *(const short8*)&As[aofl[m] + kk * 32];
#pragma unroll
      for (int n = 0; n < 4; ++n) bf[n] = *(const short8*)&Bs[bofl[n] + kk * 32];
#pragma unroll
      for (int m = 0; m < 4; ++m)
#pragma unroll
        for (int n = 0; n < 4; ++n)
          acc[m][n] = MFMA16(af[m], bf[n], acc[m][n]);
    }
    __syncthreads();
  }
#pragma unroll
  for (int m = 0; m < 4; ++m) {
    int row0 = bm + (wm << 6) + (m << 4) + (fq << 2);
#pragma unroll
    for (int n = 0; n < 4; ++n) {
      int col = bn + (wn << 6) + (n << 4) + fr;
#pragma unroll
      for (int r = 0; r < 4; ++r)
        C[(size_t)(row0 + r) * N + col] = acc[m][n][r];
    }
  }
}

// ---------------------------------------------------------------- persistent GRU layer
// 64 WGs x 64 thr (1 wave/CU). WG owns h-cols [16*wg,16*wg+16). W slice (48x1024) in
// swizzled LDS. h[t] staged per step via global_load_lds into 3-panel swizzled LDS with
// counted vmcnt. Cross-WG exchange: sc1 atomic u32 h-stores -> vmcnt(0) -> sc1 flag;
// consumers poll flags (sc1) then read h with normal cached loads (write-once addresses).
#define HWAIT(N) do { asm volatile("s_waitcnt vmcnt(" N ")" ::: "memory"); \
                      __builtin_amdgcn_sched_barrier(0); } while (0)

__global__ __launch_bounds__(64) void gru_layer(const ushort* __restrict__ W,
                                                const float* __restrict__ bih,
                                                const float* __restrict__ bhh,
                                                const float* __restrict__ xp,
                                                ushort* __restrict__ hseq,
                                                float* __restrict__ hstate,
                                                int* __restrict__ flags,
                                                int t0, int tEnd) {
  __shared__ __align__(16) ushort Wl[48 * 1024];   // 96 KB, 16B-slot ^ (row&7) swizzle
  __shared__ __align__(16) ushort Hl[3 * 8192];    // 48 KB, 3 panels (32 rows x 256 cols)
  const int lane = threadIdx.x;
  const int c0 = blockIdx.x << 4;
  const int fr = lane & 15, fq = lane >> 4, x3 = fr & 7;

  // ---- stage W (96 x 16B-wide global_load_lds), source pre-swizzled
#pragma unroll
  for (int j = 0; j < 96; ++j) {
    int row = j >> 1;                          // LDS row 0..47 (= gate*16 + cc)
    int sp7 = ((j & 1) << 6) + lane;           // 16B slot 0..127
    int slog = sp7 ^ (row & 7);
    size_t gel = (size_t)(((row >> 4) << 10) + c0 + (row & 15)) * 1024 + ((size_t)slog << 3);
    __builtin_amdgcn_global_load_lds(
        (const __attribute__((address_space(1))) unsigned*)(const void*)(W + gel),
        (__attribute__((address_space(3))) unsigned*)(void*)&Wl[j * 512], 16, 0, 0);
  }

  const int c = c0 + fr;
  const float bhr = bhh[c], bhz = bhh[1024 + c], bhn = bhh[2048 + c];
  const float bir = bih[c], biz = bih[1024 + c], bin_ = bih[2048 + c];

  float hl[2][4];
#pragma unroll
  for (int mt = 0; mt < 2; ++mt)
#pragma unroll
    for (int r = 0; r < 4; ++r) {
      int b = (mt << 4) + (fq << 2) + r;
      hl[mt][r] = (t0 == 0) ? 0.f : hstate[b * HH + c];
    }
  asm volatile("s_waitcnt vmcnt(0)" ::: "memory");   // W staged

  const int r0 = lane >> 5, sp5 = lane & 31;

  for (int t = t0; t < tEnd; ++t) {
    const int lt = t - t0;
    // prefetch gate inputs into registers (normal cached loads, stable data)
    const float* xpt = xp + (size_t)lt * (BB * 3 * HH);
    float xr[2][4], xz[2][4], xn[2][4];
#pragma unroll
    for (int mt = 0; mt < 2; ++mt)
#pragma unroll
      for (int r = 0; r < 4; ++r) {
        int b = (mt << 4) + (fq << 2) + r;
        const float* p = xpt + (size_t)b * 3072 + c;
        xr[mt][r] = p[0]; xz[mt][r] = p[1024]; xn[mt][r] = p[2048];
      }
    asm volatile("" ::: "memory");

    if (t > t0) {   // wait for all 64 WGs to publish h[t]
      int v;
      do {
        v = __hip_atomic_load(flags + lane, __ATOMIC_RELAXED, __HIP_MEMORY_SCOPE_AGENT);
        if (v < t) __builtin_amdgcn_s_sleep(1);
      } while (__any(v < t));
    }
    asm volatile("" ::: "memory");

    // stage h[t] (64 KB) via global_load_lds, panel-major + swizzle
    const ushort* hb = hseq + (size_t)lt * 32768;
    auto issue_panel = [&](int p, int buf) {
#pragma unroll
      for (int j2 = 0; j2 < 16; ++j2) {
        int row = (j2 << 1) + r0;
        int src = (row << 10) + (p << 8) + ((sp5 ^ (row & 7)) << 3);
        __builtin_amdgcn_global_load_lds(
            (const __attribute__((address_space(1))) unsigned*)(const void*)(hb + src),
            (__attribute__((address_space(3))) unsigned*)(void*)&Hl[buf * 8192 + j2 * 512],
            16, 0, 0);
      }
    };
    f32x4 acc[2][3] = {};
    auto panel_mfma = [&](int p, int buf) {
      const int hbase = buf * 8192 + fr * 256;
#pragma unroll
      for (int j = 0; j < 8; ++j) {
        int sA = ((j << 2) + fq) ^ x3;
        const short8 a0 = *(const short8*)&Hl[hbase + (sA << 3)];
        const short8 a1 = *(const short8*)&Hl[hbase + 4096 + (sA << 3)];
        int kk = (p << 3) + j;
        int sW = ((kk << 2) + fq) ^ x3;
        const short8 br = *(const short8*)&Wl[fr * 1024 + (sW << 3)];
        const short8 bz = *(const short8*)&Wl[(16 + fr) * 1024 + (sW << 3)];
        const short8 bn = *(const short8*)&Wl[(32 + fr) * 1024 + (sW << 3)];
        acc[0][0] = MFMA16(a0, br, acc[0][0]);
        acc[1][0] = MFMA16(a1, br, acc[1][0]);
        acc[0][1] = MFMA16(a0, bz, acc[0][1]);
        acc[1][1] = MFMA16(a1, bz, acc[1][1]);
        acc[0][2] = MFMA16(a0, bn, acc[0][2]);
        acc[1][2] = MFMA16(a1, bn, acc[1][2]);
      }
    };

    issue_panel(0, 0);
    issue_panel(1, 1);
    issue_panel(2, 2);
    HWAIT("32");
    panel_mfma(0, 0);
    asm volatile("s_waitcnt lgkmcnt(0)" ::: "memory");
    __builtin_amdgcn_sched_barrier(0);
    issue_panel(3, 0);
    HWAIT("32");
    panel_mfma(1, 1);
    HWAIT("16");
    panel_mfma(2, 2);
    HWAIT("0");
    panel_mfma(3, 0);

    // gates + packed sc1 h-store
    ushort* hw = hseq + (size_t)(lt + 1) * 32768;
    const int cpair = c0 + (fr & ~1);
#pragma unroll
    for (int mt = 0; mt < 2; ++mt)
#pragma unroll
      for (int r = 0; r < 4; ++r) {
        float hr = acc[mt][0][r] + bhr;
        float hz = acc[mt][1][r] + bhz;
        float hn = acc[mt][2][r] + bhn;
        float rv = 1.f / (1.f + __expf(-(xr[mt][r] + bir + hr)));
        float zv = 1.f / (1.f + __expf(-(xz[mt][r] + biz + hz)));
        float nv = tanhf(xn[mt][r] + bin_ + rv * hn);
        float h = (1.f - zv) * nv + zv * hl[mt][r];
        hl[mt][r] = h;
        unsigned me = f2b(h);
        unsigned nb = (unsigned)__shfl_xor((int)me, 1);
        unsigned word = (lane & 1) ? ((me << 16) | nb) : (me | (nb << 16));
        int b = (mt << 4) + (fq << 2) + r;
        if ((lane & 1) == mt)
          __hip_atomic_store((unsigned*)(hw + (size_t)b * HH + cpair), word,
                             __ATOMIC_RELAXED, __HIP_MEMORY_SCOPE_AGENT);
        if (t == tEnd - 1) {
          hstate[b * HH + c] = h;                                   // fp32 carry
          if ((lane & 1) == mt)
            *(unsigned*)(hseq + (size_t)b * HH + cpair) = word;     // slot 0 for next launch
        }
      }
    asm volatile("s_waitcnt vmcnt(0)" ::: "memory");   // h-stores acked at coherence point
    if (lane == 0)
      __hip_atomic_store(flags + blockIdx.x, t + 1, __ATOMIC_RELAXED, __HIP_MEMORY_SCOPE_AGENT);
  }
}

// ---------------------------------------------------------------- final FC
__global__ __launch_bounds__(256) void fc_k(const float* __restrict__ h,
                                            const float* __restrict__ Wf,
                                            const float* __restrict__ bf,
                                            float* __restrict__ out) {
  int idx = blockIdx.x * 256 + threadIdx.x;   // grid 64 -> 16384 = 32x512
  int b = idx >> 9, o = idx & 511;
  const float4* hv = (const float4*)(h + (b << 10));
  const float4* wv = (const float4*)(Wf + (o << 10));
  float s = 0.f;
#pragma unroll 8
  for (int i = 0; i < 256; ++i) {
    float4 x = hv[i], y = wv[i];
    s += x.x * y.x + x.y * y.y + x.z * y.z + x.w * y.w;
  }
  out[idx] = s + bf[o];
}

// ---------------------------------------------------------------- launch
extern "C" void kernel_launch(void* const* d_in, const int* in_sizes, int n_in,
                              void* d_out, int out_size, void* d_ws, size_t ws_size,
                              hipStream_t stream) {
  const float* x    = (const float*)d_in[0];
  const float* Wih0 = (const float*)d_in[1];
  const float* Whh0 = (const float*)d_in[2];
  const float* bih0 = (const float*)d_in[3];
  const float* bhh0 = (const float*)d_in[4];
  const float* Wih1 = (const float*)d_in[5];
  const float* Whh1 = (const float*)d_in[6];
  const float* bih1 = (const float*)d_in[7];
  const float* bhh1 = (const float*)d_in[8];
  const float* Wfc  = (const float*)d_in[9];
  const float* bfc  = (const float*)d_in[10];
  float* out = (float*)d_out;

  // workspace layout (total ~89.5 MiB)
  char* w = (char*)d_ws;
  ushort* wi0b = (ushort*)(w);                    //  3,145,728
  ushort* wh0b = (ushort*)(w + 3145728);          //  6,291,456
  ushort* wi1b = (ushort*)(w + 9437184);          //  6,291,456
  ushort* wh1b = (ushort*)(w + 15728640);         //  6,291,456
  float*  xp   = (float*)(w + 22020096);          // 50,331,648  [128,B,3H] fp32
  ushort* h1   = (ushort*)(w + 72351744);         //  8,454,144  129 slots bf16
  ushort* h2   = (ushort*)(w + 80805888);         //  8,454,144  129 slots
  float*  hs0  = (float*)(w + 89260032);          //    131,072
  float*  hs1  = (float*)(w + 89391104);          //    131,072
  int*    flg0 = (int*)(w + 89522176);            //        256
  int*    flg1 = (int*)(w + 89522432);            //        256

  init_k<<<128, 256, 0, stream>>>((unsigned int*)h1, (unsigned int*)h2, flg0, flg1);

  cast_k<<<1536, 256, 0, stream>>>(Wih0, wi0b, (3 * HH * DIN) / 4);
  cast_k<<<3072, 256, 0, stream>>>(Whh0, wh0b, (3 * HH * HH) / 4);
  cast_k<<<3072, 256, 0, stream>>>(Wih1, wi1b, (3 * HH * HH) / 4);
  cast_k<<<3072, 256, 0, stream>>>(Whh1, wh1b, (3 * HH * HH) / 4);

  for (int ch = 0; ch < 4; ++ch) {
    const int t0 = ch * CHUNK, t1 = (ch + 1) * CHUNK;
    gemm_bt<1><<<dim3(24, 32), 256, 0, stream>>>(x, wi0b, xp, 3 * HH, DIN, t0);
    gru_layer<<<64, 64, 0, stream>>>(wh0b, bih0, bhh0, xp, h1, hs0, flg0, t0, t1);
    gemm_bt<0><<<dim3(24, 32), 256, 0, stream>>>(h1 + 32768, wi1b, xp, 3 * HH, HH, 0);
    gru_layer<<<64, 64, 0, stream>>>(wh1b, bih1, bhh1, xp, h2, hs1, flg1, t0, t1);
  }

  fc_k<<<64, 256, 0, stream>>>(hs1, Wfc, bfc, out);
}